// Round 9
// baseline (400.500 us; speedup 1.0000x reference)
//
#include <hip/hip_runtime.h>

#define N_NODES 50000
#define N_EDGES 800000
#define IN_F    128
#define OUT_F   128
#define NEIG    64
#define HDIM    128
#define BN_EPSF 1e-5f
#define XB_ROWS 50048            // 50000 padded to 128
#define XB_COLS 640
#define SCAN_BLK 49              // ceil(50000/1024)
#define HSP_BLOCKS 521           // 521*96 >= 50000
#define HSP_NODES 96

typedef __attribute__((ext_vector_type(8))) short short8;
typedef __attribute__((ext_vector_type(4))) float floatx4;

// ---- workspace layout (in 4-byte units) ----
#define OFF_XB      0                                   // ushort[50048*640] -> 16,015,360 floats
#define OFF_X1F     (XB_ROWS * XB_COLS / 2)             // 16,015,360 (hs partials region)
#define OFF_X2F     (OFF_X1F + N_NODES * IN_F)          // 22,415,360 (unused)
#define OFF_WT      (OFF_X2F + N_NODES * IN_F)          // 28,815,360 (ushort[640*128] = 40,960 floats)
#define OFF_DSQRT   (OFF_WT + 40960)                    // 28,856,320
#define OFF_HS      (OFF_DSQRT + N_NODES)
#define OFF_EF      (OFF_HS + NEIG * OUT_F)
#define OFF_COLSUM  (OFF_EF + NEIG)
#define OFF_COLSQ   (OFF_COLSUM + OUT_F)
#define OFF_DEG     (OFF_COLSQ + OUT_F)
#define OFF_ROWSTART (OFF_DEG + N_NODES)
#define OFF_CSR     (OFF_ROWSTART + N_NODES + 1)
#define OFF_BSUM    (OFF_CSR + N_EDGES)                 // 64 ints
#define OFF_RANK    (OFF_BSUM + 64)                     // E ints
// end ~= 30.7M * 4B ~= 122.9 MB (< 128.3 MB proven in R0)

static __device__ inline unsigned short f2bf(float f) {
    union { float f; unsigned int u; } v; v.f = f;
    unsigned int r = (v.u + 0x7FFFu + ((v.u >> 16) & 1u)) >> 16;
    return (unsigned short)r;
}
static __device__ inline float bf2f(unsigned int u16) {
    union { unsigned int u; float f; } v; v.u = u16 << 16;
    return v.f;
}

// merged: feat2bf (blocks 0..3124) | wt (3125..3444) | zero deg+stats (3445..3673)
__global__ __launch_bounds__(256) void k_prep(const float* __restrict__ feat,
                                              const float* __restrict__ W,
                                              unsigned short* __restrict__ Xb,
                                              unsigned short* __restrict__ Wt,
                                              int* __restrict__ deg,
                                              float* __restrict__ small) {
    int b = blockIdx.x;
    if (b < 3125) {
        int t = b * 256 + threadIdx.x;           // [0, 800000)
        int n = t >> 4, c8 = (t & 15) * 8;
        float4 a = *(const float4*)&feat[n * IN_F + c8];
        float4 bb = *(const float4*)&feat[n * IN_F + c8 + 4];
        ushort4 o0, o1;
        o0.x = f2bf(a.x); o0.y = f2bf(a.y); o0.z = f2bf(a.z); o0.w = f2bf(a.w);
        o1.x = f2bf(bb.x); o1.y = f2bf(bb.y); o1.z = f2bf(bb.z); o1.w = f2bf(bb.w);
        *(ushort4*)&Xb[(size_t)n * XB_COLS + c8]     = o0;
        *(ushort4*)&Xb[(size_t)n * XB_COLS + c8 + 4] = o1;
    } else if (b < 3445) {
        int t = (b - 3125) * 256 + threadIdx.x;  // [0, 81920)
        int k = t >> 7, n = t & 127;
        Wt[n * 640 + k] = f2bf(W[k * 128 + n]);
    } else {
        int i = (b - 3445) * 256 + threadIdx.x;
        if (i < N_NODES) deg[i] = 0;
        if (i < NEIG * OUT_F + NEIG + 2 * OUT_F) small[i] = 0.0f;
    }
}

// per-edge rank within its dst bucket (atomic); deg = counts afterwards
__global__ void k_rank(int* __restrict__ deg, const int* __restrict__ dst,
                       int* __restrict__ rank) {
    int e = blockIdx.x * 256 + threadIdx.x;
    if (e < N_EDGES) rank[e] = atomicAdd(&deg[dst[e]], 1);
}

// ---- 3-stage parallel scan ----
__global__ __launch_bounds__(1024) void k_scan1(const int* __restrict__ deg,
                                                int* __restrict__ row_start,
                                                int* __restrict__ bsum) {
    __shared__ int sd[1024];
    int i = blockIdx.x * 1024 + threadIdx.x;
    int v = (i < N_NODES) ? deg[i] : 0;
    sd[threadIdx.x] = v;
    __syncthreads();
    for (int off = 1; off < 1024; off <<= 1) {
        int t = (threadIdx.x >= off) ? sd[threadIdx.x - off] : 0;
        __syncthreads();
        sd[threadIdx.x] += t;
        __syncthreads();
    }
    if (i < N_NODES) row_start[i] = sd[threadIdx.x] - v;
    if (threadIdx.x == 1023) bsum[blockIdx.x] = sd[1023];
}

__global__ void k_scan2(int* __restrict__ bsum) {
    int t = threadIdx.x;
    int orig = (t < SCAN_BLK) ? bsum[t] : 0;
    int v = orig;
    for (int off = 1; off < 64; off <<= 1) {
        int u = __shfl_up(v, off);
        if (t >= off) v += u;
    }
    if (t < SCAN_BLK) bsum[t] = v - orig;
}

__global__ __launch_bounds__(1024) void k_scan3(const int* __restrict__ deg,
                                                int* __restrict__ row_start,
                                                const int* __restrict__ bsum,
                                                float* __restrict__ dsq) {
    int i = blockIdx.x * 1024 + threadIdx.x;
    if (i < N_NODES) {
        int r = row_start[i] + bsum[blockIdx.x];
        row_start[i] = r;
        dsq[i] = rsqrtf((float)max(deg[i], 1));
    }
    if (i == 0) row_start[N_NODES] = N_EDGES;
}

// scatter csr entries, no atomics (rank precomputed)
__global__ void k_csr(const int* __restrict__ src, const int* __restrict__ dst,
                      const int* __restrict__ rank, const int* __restrict__ row_start,
                      int* __restrict__ csr_src) {
    int e = blockIdx.x * 256 + threadIdx.x;
    if (e < N_EDGES) csr_src[row_start[dst[e]] + rank[e]] = src[e];
}

// One wave per node, all-bf16 state. 8x/4x unrolled edge loop (latency hiding).
__global__ __launch_bounds__(256) void k_gather(const int* __restrict__ row_start,
                                                const int* __restrict__ csr_src,
                                                const float* __restrict__ dsq,
                                                const unsigned short* __restrict__ srcb,
                                                const unsigned short* __restrict__ prevb,
                                                const unsigned short* __restrict__ ppb,
                                                unsigned short* __restrict__ outb,
                                                const float* __restrict__ lm, int first) {
    int n = (blockIdx.x * 256 + threadIdx.x) >> 6;
    int lane = threadIdx.x & 63;
    if (n >= N_NODES) return;
    float rn = 2.0f / lm[0];
    float ax = 0.0f, ay = 0.0f;
    int beg = row_start[n], end = row_start[n + 1];
    int i = beg;
    for (; i + 8 <= end; i += 8) {
        int s0 = __builtin_amdgcn_readfirstlane(csr_src[i]);
        int s1 = __builtin_amdgcn_readfirstlane(csr_src[i + 1]);
        int s2 = __builtin_amdgcn_readfirstlane(csr_src[i + 2]);
        int s3 = __builtin_amdgcn_readfirstlane(csr_src[i + 3]);
        int s4 = __builtin_amdgcn_readfirstlane(csr_src[i + 4]);
        int s5 = __builtin_amdgcn_readfirstlane(csr_src[i + 5]);
        int s6 = __builtin_amdgcn_readfirstlane(csr_src[i + 6]);
        int s7 = __builtin_amdgcn_readfirstlane(csr_src[i + 7]);
        float c0 = dsq[s0], c1 = dsq[s1], c2 = dsq[s2], c3 = dsq[s3];
        float c4 = dsq[s4], c5 = dsq[s5], c6 = dsq[s6], c7 = dsq[s7];
        unsigned int p0 = *(const unsigned int*)&srcb[(size_t)s0 * XB_COLS + lane * 2];
        unsigned int p1 = *(const unsigned int*)&srcb[(size_t)s1 * XB_COLS + lane * 2];
        unsigned int p2 = *(const unsigned int*)&srcb[(size_t)s2 * XB_COLS + lane * 2];
        unsigned int p3 = *(const unsigned int*)&srcb[(size_t)s3 * XB_COLS + lane * 2];
        unsigned int p4 = *(const unsigned int*)&srcb[(size_t)s4 * XB_COLS + lane * 2];
        unsigned int p5 = *(const unsigned int*)&srcb[(size_t)s5 * XB_COLS + lane * 2];
        unsigned int p6 = *(const unsigned int*)&srcb[(size_t)s6 * XB_COLS + lane * 2];
        unsigned int p7 = *(const unsigned int*)&srcb[(size_t)s7 * XB_COLS + lane * 2];
        ax += c0 * bf2f(p0 & 0xffffu) + c1 * bf2f(p1 & 0xffffu)
            + c2 * bf2f(p2 & 0xffffu) + c3 * bf2f(p3 & 0xffffu)
            + c4 * bf2f(p4 & 0xffffu) + c5 * bf2f(p5 & 0xffffu)
            + c6 * bf2f(p6 & 0xffffu) + c7 * bf2f(p7 & 0xffffu);
        ay += c0 * bf2f(p0 >> 16) + c1 * bf2f(p1 >> 16)
            + c2 * bf2f(p2 >> 16) + c3 * bf2f(p3 >> 16)
            + c4 * bf2f(p4 >> 16) + c5 * bf2f(p5 >> 16)
            + c6 * bf2f(p6 >> 16) + c7 * bf2f(p7 >> 16);
    }
    for (; i + 4 <= end; i += 4) {
        int s0 = __builtin_amdgcn_readfirstlane(csr_src[i]);
        int s1 = __builtin_amdgcn_readfirstlane(csr_src[i + 1]);
        int s2 = __builtin_amdgcn_readfirstlane(csr_src[i + 2]);
        int s3 = __builtin_amdgcn_readfirstlane(csr_src[i + 3]);
        float c0 = dsq[s0], c1 = dsq[s1], c2 = dsq[s2], c3 = dsq[s3];
        unsigned int p0 = *(const unsigned int*)&srcb[(size_t)s0 * XB_COLS + lane * 2];
        unsigned int p1 = *(const unsigned int*)&srcb[(size_t)s1 * XB_COLS + lane * 2];
        unsigned int p2 = *(const unsigned int*)&srcb[(size_t)s2 * XB_COLS + lane * 2];
        unsigned int p3 = *(const unsigned int*)&srcb[(size_t)s3 * XB_COLS + lane * 2];
        ax += c0 * bf2f(p0 & 0xffffu) + c1 * bf2f(p1 & 0xffffu)
            + c2 * bf2f(p2 & 0xffffu) + c3 * bf2f(p3 & 0xffffu);
        ay += c0 * bf2f(p0 >> 16) + c1 * bf2f(p1 >> 16)
            + c2 * bf2f(p2 >> 16) + c3 * bf2f(p3 >> 16);
    }
    for (; i < end; ++i) {
        int s = __builtin_amdgcn_readfirstlane(csr_src[i]);
        float sc = dsq[s];
        unsigned int pv = *(const unsigned int*)&srcb[(size_t)s * XB_COLS + lane * 2];
        ax += sc * bf2f(pv & 0xffffu);
        ay += sc * bf2f(pv >> 16);
    }
    float ds = dsq[n];
    float a = (first ? -rn : -2.0f * rn) * ds;
    float b = first ? (rn - 1.0f) : 2.0f * (rn - 1.0f);
    unsigned int pu = *(const unsigned int*)&prevb[(size_t)n * XB_COLS + lane * 2];
    float rx = a * ax + b * bf2f(pu & 0xffffu);
    float ry = a * ay + b * bf2f(pu >> 16);
    if (ppb) {
        unsigned int qu = *(const unsigned int*)&ppb[(size_t)n * XB_COLS + lane * 2];
        rx -= bf2f(qu & 0xffffu);
        ry -= bf2f(qu >> 16);
    }
    unsigned int packed = (unsigned int)f2bf(rx) | ((unsigned int)f2bf(ry) << 16);
    *(unsigned int*)&outb[(size_t)n * XB_COLS + lane * 2] = packed;
}

// eigen-MLP: 64 blocks (one per eigenvalue), 128 threads
__global__ __launch_bounds__(128) void k_ef2(const float* __restrict__ evals,
                                             const float* __restrict__ ew0,
                                             const float* __restrict__ eb0,
                                             const float* __restrict__ ew1,
                                             const float* __restrict__ eb1,
                                             const float* __restrict__ ew2,
                                             const float* __restrict__ eb2,
                                             float* __restrict__ ef) {
    __shared__ float z0[HDIM];
    __shared__ float red[HDIM];
    int i = blockIdx.x, j = threadIdx.x;
    float ev = evals[i];
    z0[j] = fmaxf(0.0f, ev * ew0[j] + eb0[j]);
    __syncthreads();
    float s0 = 0.f, s1 = 0.f, s2 = 0.f, s3 = 0.f;
    for (int h = 0; h < HDIM; h += 4) {
        s0 += z0[h]     * ew1[(h) * HDIM + j];
        s1 += z0[h + 1] * ew1[(h + 1) * HDIM + j];
        s2 += z0[h + 2] * ew1[(h + 2) * HDIM + j];
        s3 += z0[h + 3] * ew1[(h + 3) * HDIM + j];
    }
    float z1 = fmaxf(0.0f, eb1[j] + s0 + s1 + s2 + s3);
    red[j] = z1 * ew2[j];
    __syncthreads();
    for (int off = 64; off > 0; off >>= 1) {
        if (j < off) red[j] += red[j + off];
        __syncthreads();
    }
    if (j == 0) ef[i] = red[0] + eb2[0];
}

// hs partial: block b handles 96 nodes; partial C[64][128] -> partials[b]
__global__ __launch_bounds__(256) void k_hs_partial2(const float* __restrict__ evecs,
                                                     const float* __restrict__ feat,
                                                     float* __restrict__ partials) {
    __shared__ float sEv[32 * NEIG];    // 8 KB
    __shared__ float sFt[32 * IN_F];    // 16 KB
    int t = threadIdx.x;
    int e0 = (t >> 5) * 8;
    int f0 = (t & 31) * 4;
    float acc[8][4];
#pragma unroll
    for (int r = 0; r < 8; ++r)
#pragma unroll
        for (int c = 0; c < 4; ++c) acc[r][c] = 0.0f;

    int n0 = blockIdx.x * HSP_NODES;
    for (int ch = 0; ch < HSP_NODES; ch += 32) {
        int base = n0 + ch;
        {
            int r = t >> 3, c = (t & 7) * 8;
            int n = base + r;
            float4 a, b;
            if (n < N_NODES) {
                a = *(const float4*)&evecs[(size_t)n * NEIG + c];
                b = *(const float4*)&evecs[(size_t)n * NEIG + c + 4];
            } else {
                a = make_float4(0, 0, 0, 0); b = a;
            }
            *(float4*)&sEv[r * NEIG + c] = a;
            *(float4*)&sEv[r * NEIG + c + 4] = b;
        }
        {
            int r = t >> 3, c = (t & 7) * 16;
            int n = base + r;
#pragma unroll
            for (int q = 0; q < 4; ++q) {
                float4 v = (n < N_NODES) ? *(const float4*)&feat[(size_t)n * IN_F + c + q * 4]
                                         : make_float4(0, 0, 0, 0);
                *(float4*)&sFt[r * IN_F + c + q * 4] = v;
            }
        }
        __syncthreads();
#pragma unroll 2
        for (int i = 0; i < 32; ++i) {
            float4 ev0 = *(float4*)&sEv[i * NEIG + e0];
            float4 ev1 = *(float4*)&sEv[i * NEIG + e0 + 4];
            float4 fv  = *(float4*)&sFt[i * IN_F + f0];
            float evv[8] = {ev0.x, ev0.y, ev0.z, ev0.w, ev1.x, ev1.y, ev1.z, ev1.w};
#pragma unroll
            for (int r = 0; r < 8; ++r) {
                acc[r][0] += evv[r] * fv.x;
                acc[r][1] += evv[r] * fv.y;
                acc[r][2] += evv[r] * fv.z;
                acc[r][3] += evv[r] * fv.w;
            }
        }
        __syncthreads();
    }
    float* p = &partials[(size_t)blockIdx.x * (NEIG * IN_F)];
#pragma unroll
    for (int r = 0; r < 8; ++r)
        *(float4*)&p[(e0 + r) * IN_F + f0] = make_float4(acc[r][0], acc[r][1], acc[r][2], acc[r][3]);
}

// reduce partials -> hs_small
__global__ void k_hs_reduce(const float* __restrict__ partials, float* __restrict__ hs_small) {
    int p = blockIdx.x * 256 + threadIdx.x;
    float s = 0.0f;
    for (int j = 0; j < HSP_BLOCKS; ++j) s += partials[(size_t)j * (NEIG * IN_F) + p];
    hs_small[p] = s;
}

// Xb[n, 512+f] = bf16( sum_e evecs[n,e] * ef[e] * hs_small[e,f] ); 32 nodes/block
__global__ __launch_bounds__(256) void k_hs_apply2(unsigned short* __restrict__ Xb,
                                                   const float* __restrict__ evecs,
                                                   const float* __restrict__ hs_small,
                                                   const float* __restrict__ ef) {
    __shared__ float sShs[NEIG * HDIM];
    __shared__ float sEv[32 * NEIG];
    int t = threadIdx.x;
    int n0 = blockIdx.x * 32;
    {
        float efv = ef[t >> 2];
        int pbase = t * 32;
#pragma unroll
        for (int q = 0; q < 8; ++q) {
            float4 v = *(const float4*)&hs_small[pbase + q * 4];
            v.x *= efv; v.y *= efv; v.z *= efv; v.w *= efv;
            *(float4*)&sShs[pbase + q * 4] = v;
        }
    }
    {
        int r = t >> 3, c = (t & 7) * 8;
        int n = n0 + r;
        float4 a, b;
        if (n < N_NODES) {
            a = *(const float4*)&evecs[(size_t)n * NEIG + c];
            b = *(const float4*)&evecs[(size_t)n * NEIG + c + 4];
        } else {
            a = make_float4(0, 0, 0, 0); b = a;
        }
        *(float4*)&sEv[r * NEIG + c] = a;
        *(float4*)&sEv[r * NEIG + c + 4] = b;
    }
    __syncthreads();
    int nb = (t >> 5) * 4;
    int f0 = (t & 31) * 4;
    float acc[4][4];
#pragma unroll
    for (int q = 0; q < 4; ++q)
#pragma unroll
        for (int c = 0; c < 4; ++c) acc[q][c] = 0.0f;
    for (int e = 0; e < NEIG; ++e) {
        float4 sv = *(float4*)&sShs[e * HDIM + f0];
#pragma unroll
        for (int q = 0; q < 4; ++q) {
            float evv = sEv[(nb + q) * NEIG + e];
            acc[q][0] += evv * sv.x;
            acc[q][1] += evv * sv.y;
            acc[q][2] += evv * sv.z;
            acc[q][3] += evv * sv.w;
        }
    }
#pragma unroll
    for (int q = 0; q < 4; ++q) {
        int n = n0 + nb + q;
        if (n < N_NODES) {
            ushort4 o;
            o.x = f2bf(acc[q][0]); o.y = f2bf(acc[q][1]);
            o.z = f2bf(acc[q][2]); o.w = f2bf(acc[q][3]);
            *(ushort4*)&Xb[(size_t)n * XB_COLS + 4 * IN_F + f0] = o;
        }
    }
}

// MFMA bf16 GEMM with fused BN column-stats.
// Epilogue: shfl-reduce col partials across the 4 quads (same m16 = same col),
// write per-wave LDS slot (single writer, conflict-free), then 128 threads
// reduce 4 waves -> 1 global atomic per column per block. NO LDS atomics.
__global__ __launch_bounds__(256) void k_gemm(const unsigned short* __restrict__ Xb,
                                              const unsigned short* __restrict__ Wt,
                                              const float* __restrict__ bias,
                                              float* __restrict__ out,
                                              float* __restrict__ colsum,
                                              float* __restrict__ colsq) {
    __shared__ unsigned short sA[128 * 32];
    __shared__ unsigned short sB[128 * 32];
    __shared__ float cs[4][OUT_F];
    __shared__ float cq[4][OUT_F];
    int tid = threadIdx.x;
    int wave = tid >> 6, lane = tid & 63;
    int quad = lane >> 4, m16 = lane & 15;
    int row0 = blockIdx.x * 128;

    floatx4 acc[2][8];
#pragma unroll
    for (int mt = 0; mt < 2; ++mt)
#pragma unroll
        for (int nt = 0; nt < 8; ++nt) acc[mt][nt] = (floatx4)(0.0f);

    int r  = tid >> 2;
    int c8 = (tid & 3) * 8;
    int gr0 = min(row0 + r, N_NODES - 1);
    int gr1 = min(row0 + r + 64, N_NODES - 1);

    for (int k0 = 0; k0 < 640; k0 += 32) {
        *(uint4*)&sA[r * 32 + c8]        = *(const uint4*)&Xb[(size_t)gr0 * XB_COLS + k0 + c8];
        *(uint4*)&sA[(r + 64) * 32 + c8] = *(const uint4*)&Xb[(size_t)gr1 * XB_COLS + k0 + c8];
        *(uint4*)&sB[r * 32 + c8]        = *(const uint4*)&Wt[r * 640 + k0 + c8];
        *(uint4*)&sB[(r + 64) * 32 + c8] = *(const uint4*)&Wt[(r + 64) * 640 + k0 + c8];
        __syncthreads();
        short8 a0 = *(short8*)&sA[(wave * 32 + m16) * 32 + quad * 8];
        short8 a1 = *(short8*)&sA[(wave * 32 + 16 + m16) * 32 + quad * 8];
#pragma unroll
        for (int nt = 0; nt < 8; ++nt) {
            short8 b = *(short8*)&sB[(nt * 16 + m16) * 32 + quad * 8];
            acc[0][nt] = __builtin_amdgcn_mfma_f32_16x16x32_bf16(a0, b, acc[0][nt], 0, 0, 0);
            acc[1][nt] = __builtin_amdgcn_mfma_f32_16x16x32_bf16(a1, b, acc[1][nt], 0, 0, 0);
        }
        __syncthreads();
    }
#pragma unroll
    for (int nt = 0; nt < 8; ++nt) {
        int col = nt * 16 + m16;
        float bb = bias[col];
        float sv = 0.0f, sq = 0.0f;
#pragma unroll
        for (int mt = 0; mt < 2; ++mt) {
            int rbase = row0 + wave * 32 + mt * 16 + quad * 4;
#pragma unroll
            for (int reg = 0; reg < 4; ++reg) {
                int row = rbase + reg;
                if (row < N_NODES) {
                    float w = acc[mt][nt][reg] + bb;
                    out[(size_t)row * OUT_F + col] = w;
                    sv += w;
                    sq += w * w;
                }
            }
        }
        // reduce across the 4 quads (lanes with same m16 hold same col)
        sv += __shfl_down(sv, 32); sq += __shfl_down(sq, 32);
        sv += __shfl_down(sv, 16); sq += __shfl_down(sq, 16);
        if (lane < 16) { cs[wave][col] = sv; cq[wave][col] = sq; }
    }
    __syncthreads();
    if (tid < OUT_F) {
        float s = cs[0][tid] + cs[1][tid] + cs[2][tid] + cs[3][tid];
        float q = cq[0][tid] + cq[1][tid] + cq[2][tid] + cq[3][tid];
        atomicAdd(&colsum[tid], s);
        atomicAdd(&colsq[tid], q);
    }
}

__global__ void k_bn_apply(float* __restrict__ out, const float* __restrict__ colsum,
                           const float* __restrict__ colsq, const float* __restrict__ gamma,
                           const float* __restrict__ beta) {
    int t = blockIdx.x * 256 + threadIdx.x;
    int n = t >> 5, c = t & 31;
    float4 v = *(float4*)&out[n * OUT_F + c * 4];
    float4 s = *(const float4*)&colsum[c * 4];
    float4 q = *(const float4*)&colsq[c * 4];
    float4 g = *(const float4*)&gamma[c * 4];
    float4 b = *(const float4*)&beta[c * 4];
    const float invN = 1.0f / (float)N_NODES;
    float mux = s.x * invN, muy = s.y * invN, muz = s.z * invN, muw = s.w * invN;
    float ix = rsqrtf(q.x * invN - mux * mux + BN_EPSF);
    float iy = rsqrtf(q.y * invN - muy * muy + BN_EPSF);
    float iz = rsqrtf(q.z * invN - muz * muz + BN_EPSF);
    float iw = rsqrtf(q.w * invN - muw * muw + BN_EPSF);
    v.x = fmaxf(0.0f, (v.x - mux) * ix * g.x + b.x);
    v.y = fmaxf(0.0f, (v.y - muy) * iy * g.y + b.y);
    v.z = fmaxf(0.0f, (v.z - muz) * iz * g.z + b.z);
    v.w = fmaxf(0.0f, (v.w - muw) * iw * g.w + b.w);
    *(float4*)&out[n * OUT_F + c * 4] = v;
}

extern "C" void kernel_launch(void* const* d_in, const int* in_sizes, int n_in,
                              void* d_out, int out_size, void* d_ws, size_t ws_size,
                              hipStream_t stream) {
    const float* feature    = (const float*)d_in[0];
    const float* lin_w      = (const float*)d_in[1];
    const float* lin_b      = (const float*)d_in[2];
    const float* ew0        = (const float*)d_in[3];
    const float* eb0        = (const float*)d_in[4];
    const float* ew1        = (const float*)d_in[5];
    const float* eb1        = (const float*)d_in[6];
    const float* ew2        = (const float*)d_in[7];
    const float* eb2        = (const float*)d_in[8];
    const float* bn_gamma   = (const float*)d_in[9];
    const float* bn_beta    = (const float*)d_in[10];
    const float* lambda_max = (const float*)d_in[11];
    const float* evecs      = (const float*)d_in[12];
    const float* evals      = (const float*)d_in[13];
    const int*   edge_src   = (const int*)d_in[14];
    const int*   edge_dst   = (const int*)d_in[15];

    float* out = (float*)d_out;
    float* ws  = (float*)d_ws;
    unsigned short* Xb = (unsigned short*)(ws + OFF_XB);
    unsigned short* Wt = (unsigned short*)(ws + OFF_WT);
    float* dsq      = ws + OFF_DSQRT;
    float* hs_small = ws + OFF_HS;
    float* ef       = ws + OFF_EF;
    float* colsum   = ws + OFF_COLSUM;
    float* colsq    = ws + OFF_COLSQ;
    int*   deg      = (int*)(ws + OFF_DEG);
    int*   row_start= (int*)(ws + OFF_ROWSTART);
    int*   csr_src  = (int*)(ws + OFF_CSR);
    int*   bsum     = (int*)(ws + OFF_BSUM);
    int*   rank     = (int*)(ws + OFF_RANK);
    float* partials = ws + OFF_X1F;

    // ---- prep (feat->bf16, W->Wt bf16, zero deg/stats) + CSR build ----
    k_prep<<<3674, 256, 0, stream>>>(feature, lin_w, Xb, Wt, deg, hs_small);
    k_rank<<<(N_EDGES + 255) / 256, 256, 0, stream>>>(deg, edge_dst, rank);
    k_scan1<<<SCAN_BLK, 1024, 0, stream>>>(deg, row_start, bsum);
    k_scan2<<<1, 64, 0, stream>>>(bsum);
    k_scan3<<<SCAN_BLK, 1024, 0, stream>>>(deg, row_start, bsum, dsq);
    k_csr<<<(N_EDGES + 255) / 256, 256, 0, stream>>>(edge_src, edge_dst, rank, row_start, csr_src);

    // ---- Chebyshev recurrence (all-bf16 state in Xb column slots) ----
    const int GBLK = (N_NODES * 64 + 255) / 256;
    k_gather<<<GBLK, 256, 0, stream>>>(row_start, csr_src, dsq,
                                       Xb + 0, Xb + 0, (const unsigned short*)nullptr,
                                       Xb + IN_F, lambda_max, 1);
    k_gather<<<GBLK, 256, 0, stream>>>(row_start, csr_src, dsq,
                                       Xb + IN_F, Xb + IN_F, Xb + 0,
                                       Xb + 2 * IN_F, lambda_max, 0);
    k_gather<<<GBLK, 256, 0, stream>>>(row_start, csr_src, dsq,
                                       Xb + 2 * IN_F, Xb + 2 * IN_F, Xb + IN_F,
                                       Xb + 3 * IN_F, lambda_max, 0);

    // ---- eigen block ----
    k_ef2<<<NEIG, 128, 0, stream>>>(evals, ew0, eb0, ew1, eb1, ew2, eb2, ef);
    k_hs_partial2<<<HSP_BLOCKS, 256, 0, stream>>>(evecs, feature, partials);
    k_hs_reduce<<<32, 256, 0, stream>>>(partials, hs_small);
    k_hs_apply2<<<(N_NODES + 31) / 32, 256, 0, stream>>>(Xb, evecs, hs_small, ef);

    // ---- MFMA linear (+BN stats) + BN apply ----
    k_gemm<<<(N_NODES + 127) / 128, 256, 0, stream>>>(Xb, Wt, lin_b, out, colsum, colsq);
    k_bn_apply<<<(N_NODES * 32) / 256, 256, 0, stream>>>(out, colsum, colsq, bn_gamma, bn_beta);
}

// Round 10
// 369.948 us; speedup vs baseline: 1.0826x; 1.0826x over previous
//
#include <hip/hip_runtime.h>

#define N_NODES 50000
#define N_EDGES 800000
#define IN_F    128
#define OUT_F   128
#define NEIG    64
#define HDIM    128
#define BN_EPSF 1e-5f
#define XB_ROWS 50048            // 50000 padded to 128
#define XB_COLS 640
#define SCAN_BLK 49              // ceil(50000/1024)
#define HSP_BLOCKS 521           // 521*96 >= 50000
#define HSP_NODES 96
#define RED_CHUNK 33             // ceil(521/16)
#define RED_SPLIT 16

typedef __attribute__((ext_vector_type(8))) short short8;
typedef __attribute__((ext_vector_type(4))) float floatx4;

// ---- workspace layout (in 4-byte units) ----
#define OFF_XB      0                                   // ushort[50048*640] -> 16,015,360 floats
#define OFF_X1F     (XB_ROWS * XB_COLS / 2)             // 16,015,360 (hs partials region)
#define OFF_X2F     (OFF_X1F + N_NODES * IN_F)          // 22,415,360 (unused)
#define OFF_WT      (OFF_X2F + N_NODES * IN_F)          // 28,815,360 (ushort[640*128] = 40,960 floats)
#define OFF_DSQRT   (OFF_WT + 40960)                    // 28,856,320
#define OFF_HS      (OFF_DSQRT + N_NODES)
#define OFF_EF      (OFF_HS + NEIG * OUT_F)
#define OFF_COLSUM  (OFF_EF + NEIG)
#define OFF_COLSQ   (OFF_COLSUM + OUT_F)
#define OFF_DEG     (OFF_COLSQ + OUT_F)
#define OFF_ROWSTART (OFF_DEG + N_NODES)
#define OFF_CSR     (OFF_ROWSTART + N_NODES + 1)
#define OFF_BSUM    (OFF_CSR + N_EDGES)                 // 64 ints
#define OFF_RANK    (OFF_BSUM + 64)                     // E ints
// end ~= 30.7M * 4B ~= 122.9 MB (< 128.3 MB proven in R0)

static __device__ inline unsigned short f2bf(float f) {
    union { float f; unsigned int u; } v; v.f = f;
    unsigned int r = (v.u + 0x7FFFu + ((v.u >> 16) & 1u)) >> 16;
    return (unsigned short)r;
}
static __device__ inline float bf2f(unsigned int u16) {
    union { unsigned int u; float f; } v; v.u = u16 << 16;
    return v.f;
}

// merged: feat2bf (blocks 0..3124) | wt (3125..3444) | zero deg+stats (3445..3673)
__global__ __launch_bounds__(256) void k_prep(const float* __restrict__ feat,
                                              const float* __restrict__ W,
                                              unsigned short* __restrict__ Xb,
                                              unsigned short* __restrict__ Wt,
                                              int* __restrict__ deg,
                                              float* __restrict__ small) {
    int b = blockIdx.x;
    if (b < 3125) {
        int t = b * 256 + threadIdx.x;           // [0, 800000)
        int n = t >> 4, c8 = (t & 15) * 8;
        float4 a = *(const float4*)&feat[n * IN_F + c8];
        float4 bb = *(const float4*)&feat[n * IN_F + c8 + 4];
        ushort4 o0, o1;
        o0.x = f2bf(a.x); o0.y = f2bf(a.y); o0.z = f2bf(a.z); o0.w = f2bf(a.w);
        o1.x = f2bf(bb.x); o1.y = f2bf(bb.y); o1.z = f2bf(bb.z); o1.w = f2bf(bb.w);
        *(ushort4*)&Xb[(size_t)n * XB_COLS + c8]     = o0;
        *(ushort4*)&Xb[(size_t)n * XB_COLS + c8 + 4] = o1;
    } else if (b < 3445) {
        int t = (b - 3125) * 256 + threadIdx.x;  // [0, 81920)
        int k = t >> 7, n = t & 127;
        Wt[n * 640 + k] = f2bf(W[k * 128 + n]);
    } else {
        int i = (b - 3445) * 256 + threadIdx.x;
        if (i < N_NODES) deg[i] = 0;
        if (i < NEIG * OUT_F + NEIG + 2 * OUT_F) small[i] = 0.0f;
    }
}

// per-edge rank within its dst bucket (atomic); deg = counts afterwards
__global__ void k_rank(int* __restrict__ deg, const int* __restrict__ dst,
                       int* __restrict__ rank) {
    int e = blockIdx.x * 256 + threadIdx.x;
    if (e < N_EDGES) rank[e] = atomicAdd(&deg[dst[e]], 1);
}

// ---- 3-stage parallel scan ----
__global__ __launch_bounds__(1024) void k_scan1(const int* __restrict__ deg,
                                                int* __restrict__ row_start,
                                                int* __restrict__ bsum) {
    __shared__ int sd[1024];
    int i = blockIdx.x * 1024 + threadIdx.x;
    int v = (i < N_NODES) ? deg[i] : 0;
    sd[threadIdx.x] = v;
    __syncthreads();
    for (int off = 1; off < 1024; off <<= 1) {
        int t = (threadIdx.x >= off) ? sd[threadIdx.x - off] : 0;
        __syncthreads();
        sd[threadIdx.x] += t;
        __syncthreads();
    }
    if (i < N_NODES) row_start[i] = sd[threadIdx.x] - v;
    if (threadIdx.x == 1023) bsum[blockIdx.x] = sd[1023];
}

__global__ void k_scan2(int* __restrict__ bsum) {
    int t = threadIdx.x;
    int orig = (t < SCAN_BLK) ? bsum[t] : 0;
    int v = orig;
    for (int off = 1; off < 64; off <<= 1) {
        int u = __shfl_up(v, off);
        if (t >= off) v += u;
    }
    if (t < SCAN_BLK) bsum[t] = v - orig;
}

__global__ __launch_bounds__(1024) void k_scan3(const int* __restrict__ deg,
                                                int* __restrict__ row_start,
                                                const int* __restrict__ bsum,
                                                float* __restrict__ dsq) {
    int i = blockIdx.x * 1024 + threadIdx.x;
    if (i < N_NODES) {
        int r = row_start[i] + bsum[blockIdx.x];
        row_start[i] = r;
        dsq[i] = rsqrtf((float)max(deg[i], 1));
    }
    if (i == 0) row_start[N_NODES] = N_EDGES;
}

// scatter csr entries, no atomics (rank precomputed)
__global__ void k_csr(const int* __restrict__ src, const int* __restrict__ dst,
                      const int* __restrict__ rank, const int* __restrict__ row_start,
                      int* __restrict__ csr_src) {
    int e = blockIdx.x * 256 + threadIdx.x;
    if (e < N_EDGES) csr_src[row_start[dst[e]] + rank[e]] = src[e];
}

// One wave per node, all-bf16 state. 8x/4x unrolled edge loop (latency hiding).
__global__ __launch_bounds__(256) void k_gather(const int* __restrict__ row_start,
                                                const int* __restrict__ csr_src,
                                                const float* __restrict__ dsq,
                                                const unsigned short* __restrict__ srcb,
                                                const unsigned short* __restrict__ prevb,
                                                const unsigned short* __restrict__ ppb,
                                                unsigned short* __restrict__ outb,
                                                const float* __restrict__ lm, int first) {
    int n = (blockIdx.x * 256 + threadIdx.x) >> 6;
    int lane = threadIdx.x & 63;
    if (n >= N_NODES) return;
    float rn = 2.0f / lm[0];
    float ax = 0.0f, ay = 0.0f;
    int beg = row_start[n], end = row_start[n + 1];
    int i = beg;
    for (; i + 8 <= end; i += 8) {
        int s0 = __builtin_amdgcn_readfirstlane(csr_src[i]);
        int s1 = __builtin_amdgcn_readfirstlane(csr_src[i + 1]);
        int s2 = __builtin_amdgcn_readfirstlane(csr_src[i + 2]);
        int s3 = __builtin_amdgcn_readfirstlane(csr_src[i + 3]);
        int s4 = __builtin_amdgcn_readfirstlane(csr_src[i + 4]);
        int s5 = __builtin_amdgcn_readfirstlane(csr_src[i + 5]);
        int s6 = __builtin_amdgcn_readfirstlane(csr_src[i + 6]);
        int s7 = __builtin_amdgcn_readfirstlane(csr_src[i + 7]);
        float c0 = dsq[s0], c1 = dsq[s1], c2 = dsq[s2], c3 = dsq[s3];
        float c4 = dsq[s4], c5 = dsq[s5], c6 = dsq[s6], c7 = dsq[s7];
        unsigned int p0 = *(const unsigned int*)&srcb[(size_t)s0 * XB_COLS + lane * 2];
        unsigned int p1 = *(const unsigned int*)&srcb[(size_t)s1 * XB_COLS + lane * 2];
        unsigned int p2 = *(const unsigned int*)&srcb[(size_t)s2 * XB_COLS + lane * 2];
        unsigned int p3 = *(const unsigned int*)&srcb[(size_t)s3 * XB_COLS + lane * 2];
        unsigned int p4 = *(const unsigned int*)&srcb[(size_t)s4 * XB_COLS + lane * 2];
        unsigned int p5 = *(const unsigned int*)&srcb[(size_t)s5 * XB_COLS + lane * 2];
        unsigned int p6 = *(const unsigned int*)&srcb[(size_t)s6 * XB_COLS + lane * 2];
        unsigned int p7 = *(const unsigned int*)&srcb[(size_t)s7 * XB_COLS + lane * 2];
        ax += c0 * bf2f(p0 & 0xffffu) + c1 * bf2f(p1 & 0xffffu)
            + c2 * bf2f(p2 & 0xffffu) + c3 * bf2f(p3 & 0xffffu)
            + c4 * bf2f(p4 & 0xffffu) + c5 * bf2f(p5 & 0xffffu)
            + c6 * bf2f(p6 & 0xffffu) + c7 * bf2f(p7 & 0xffffu);
        ay += c0 * bf2f(p0 >> 16) + c1 * bf2f(p1 >> 16)
            + c2 * bf2f(p2 >> 16) + c3 * bf2f(p3 >> 16)
            + c4 * bf2f(p4 >> 16) + c5 * bf2f(p5 >> 16)
            + c6 * bf2f(p6 >> 16) + c7 * bf2f(p7 >> 16);
    }
    for (; i + 4 <= end; i += 4) {
        int s0 = __builtin_amdgcn_readfirstlane(csr_src[i]);
        int s1 = __builtin_amdgcn_readfirstlane(csr_src[i + 1]);
        int s2 = __builtin_amdgcn_readfirstlane(csr_src[i + 2]);
        int s3 = __builtin_amdgcn_readfirstlane(csr_src[i + 3]);
        float c0 = dsq[s0], c1 = dsq[s1], c2 = dsq[s2], c3 = dsq[s3];
        unsigned int p0 = *(const unsigned int*)&srcb[(size_t)s0 * XB_COLS + lane * 2];
        unsigned int p1 = *(const unsigned int*)&srcb[(size_t)s1 * XB_COLS + lane * 2];
        unsigned int p2 = *(const unsigned int*)&srcb[(size_t)s2 * XB_COLS + lane * 2];
        unsigned int p3 = *(const unsigned int*)&srcb[(size_t)s3 * XB_COLS + lane * 2];
        ax += c0 * bf2f(p0 & 0xffffu) + c1 * bf2f(p1 & 0xffffu)
            + c2 * bf2f(p2 & 0xffffu) + c3 * bf2f(p3 & 0xffffu);
        ay += c0 * bf2f(p0 >> 16) + c1 * bf2f(p1 >> 16)
            + c2 * bf2f(p2 >> 16) + c3 * bf2f(p3 >> 16);
    }
    for (; i < end; ++i) {
        int s = __builtin_amdgcn_readfirstlane(csr_src[i]);
        float sc = dsq[s];
        unsigned int pv = *(const unsigned int*)&srcb[(size_t)s * XB_COLS + lane * 2];
        ax += sc * bf2f(pv & 0xffffu);
        ay += sc * bf2f(pv >> 16);
    }
    float ds = dsq[n];
    float a = (first ? -rn : -2.0f * rn) * ds;
    float b = first ? (rn - 1.0f) : 2.0f * (rn - 1.0f);
    unsigned int pu = *(const unsigned int*)&prevb[(size_t)n * XB_COLS + lane * 2];
    float rx = a * ax + b * bf2f(pu & 0xffffu);
    float ry = a * ay + b * bf2f(pu >> 16);
    if (ppb) {
        unsigned int qu = *(const unsigned int*)&ppb[(size_t)n * XB_COLS + lane * 2];
        rx -= bf2f(qu & 0xffffu);
        ry -= bf2f(qu >> 16);
    }
    unsigned int packed = (unsigned int)f2bf(rx) | ((unsigned int)f2bf(ry) << 16);
    *(unsigned int*)&outb[(size_t)n * XB_COLS + lane * 2] = packed;
}

// eigen-MLP: 64 blocks (one per eigenvalue), 128 threads
__global__ __launch_bounds__(128) void k_ef2(const float* __restrict__ evals,
                                             const float* __restrict__ ew0,
                                             const float* __restrict__ eb0,
                                             const float* __restrict__ ew1,
                                             const float* __restrict__ eb1,
                                             const float* __restrict__ ew2,
                                             const float* __restrict__ eb2,
                                             float* __restrict__ ef) {
    __shared__ float z0[HDIM];
    __shared__ float red[HDIM];
    int i = blockIdx.x, j = threadIdx.x;
    float ev = evals[i];
    z0[j] = fmaxf(0.0f, ev * ew0[j] + eb0[j]);
    __syncthreads();
    float s0 = 0.f, s1 = 0.f, s2 = 0.f, s3 = 0.f;
    for (int h = 0; h < HDIM; h += 4) {
        s0 += z0[h]     * ew1[(h) * HDIM + j];
        s1 += z0[h + 1] * ew1[(h + 1) * HDIM + j];
        s2 += z0[h + 2] * ew1[(h + 2) * HDIM + j];
        s3 += z0[h + 3] * ew1[(h + 3) * HDIM + j];
    }
    float z1 = fmaxf(0.0f, eb1[j] + s0 + s1 + s2 + s3);
    red[j] = z1 * ew2[j];
    __syncthreads();
    for (int off = 64; off > 0; off >>= 1) {
        if (j < off) red[j] += red[j + off];
        __syncthreads();
    }
    if (j == 0) ef[i] = red[0] + eb2[0];
}

// hs partial: block b handles 96 nodes; partial C[64][128] -> partials[b]
__global__ __launch_bounds__(256) void k_hs_partial2(const float* __restrict__ evecs,
                                                     const float* __restrict__ feat,
                                                     float* __restrict__ partials) {
    __shared__ float sEv[32 * NEIG];    // 8 KB
    __shared__ float sFt[32 * IN_F];    // 16 KB
    int t = threadIdx.x;
    int e0 = (t >> 5) * 8;
    int f0 = (t & 31) * 4;
    float acc[8][4];
#pragma unroll
    for (int r = 0; r < 8; ++r)
#pragma unroll
        for (int c = 0; c < 4; ++c) acc[r][c] = 0.0f;

    int n0 = blockIdx.x * HSP_NODES;
    for (int ch = 0; ch < HSP_NODES; ch += 32) {
        int base = n0 + ch;
        {
            int r = t >> 3, c = (t & 7) * 8;
            int n = base + r;
            float4 a, b;
            if (n < N_NODES) {
                a = *(const float4*)&evecs[(size_t)n * NEIG + c];
                b = *(const float4*)&evecs[(size_t)n * NEIG + c + 4];
            } else {
                a = make_float4(0, 0, 0, 0); b = a;
            }
            *(float4*)&sEv[r * NEIG + c] = a;
            *(float4*)&sEv[r * NEIG + c + 4] = b;
        }
        {
            int r = t >> 3, c = (t & 7) * 16;
            int n = base + r;
#pragma unroll
            for (int q = 0; q < 4; ++q) {
                float4 v = (n < N_NODES) ? *(const float4*)&feat[(size_t)n * IN_F + c + q * 4]
                                         : make_float4(0, 0, 0, 0);
                *(float4*)&sFt[r * IN_F + c + q * 4] = v;
            }
        }
        __syncthreads();
#pragma unroll 2
        for (int i = 0; i < 32; ++i) {
            float4 ev0 = *(float4*)&sEv[i * NEIG + e0];
            float4 ev1 = *(float4*)&sEv[i * NEIG + e0 + 4];
            float4 fv  = *(float4*)&sFt[i * IN_F + f0];
            float evv[8] = {ev0.x, ev0.y, ev0.z, ev0.w, ev1.x, ev1.y, ev1.z, ev1.w};
#pragma unroll
            for (int r = 0; r < 8; ++r) {
                acc[r][0] += evv[r] * fv.x;
                acc[r][1] += evv[r] * fv.y;
                acc[r][2] += evv[r] * fv.z;
                acc[r][3] += evv[r] * fv.w;
            }
        }
        __syncthreads();
    }
    float* p = &partials[(size_t)blockIdx.x * (NEIG * IN_F)];
#pragma unroll
    for (int r = 0; r < 8; ++r)
        *(float4*)&p[(e0 + r) * IN_F + f0] = make_float4(acc[r][0], acc[r][1], acc[r][2], acc[r][3]);
}

// split reduce: 32 element-groups x 16 j-chunks; atomicAdd into pre-zeroed hs_small
__global__ __launch_bounds__(256) void k_hs_reduce(const float* __restrict__ partials,
                                                   float* __restrict__ hs_small) {
    int grp   = blockIdx.x & 31;        // element group (256 elems each)
    int chunk = blockIdx.x >> 5;        // j-chunk 0..15
    int idx = grp * 256 + threadIdx.x;  // 0..8191
    int j0 = chunk * RED_CHUNK;
    int j1 = min(j0 + RED_CHUNK, HSP_BLOCKS);
    float s = 0.0f;
    for (int j = j0; j < j1; ++j) s += partials[(size_t)j * (NEIG * IN_F) + idx];
    atomicAdd(&hs_small[idx], s);
}

// Xb[n, 512+f] = bf16( sum_e evecs[n,e] * ef[e] * hs_small[e,f] ); 32 nodes/block
__global__ __launch_bounds__(256) void k_hs_apply2(unsigned short* __restrict__ Xb,
                                                   const float* __restrict__ evecs,
                                                   const float* __restrict__ hs_small,
                                                   const float* __restrict__ ef) {
    __shared__ float sShs[NEIG * HDIM];
    __shared__ float sEv[32 * NEIG];
    int t = threadIdx.x;
    int n0 = blockIdx.x * 32;
    {
        float efv = ef[t >> 2];
        int pbase = t * 32;
#pragma unroll
        for (int q = 0; q < 8; ++q) {
            float4 v = *(const float4*)&hs_small[pbase + q * 4];
            v.x *= efv; v.y *= efv; v.z *= efv; v.w *= efv;
            *(float4*)&sShs[pbase + q * 4] = v;
        }
    }
    {
        int r = t >> 3, c = (t & 7) * 8;
        int n = n0 + r;
        float4 a, b;
        if (n < N_NODES) {
            a = *(const float4*)&evecs[(size_t)n * NEIG + c];
            b = *(const float4*)&evecs[(size_t)n * NEIG + c + 4];
        } else {
            a = make_float4(0, 0, 0, 0); b = a;
        }
        *(float4*)&sEv[r * NEIG + c] = a;
        *(float4*)&sEv[r * NEIG + c + 4] = b;
    }
    __syncthreads();
    int nb = (t >> 5) * 4;
    int f0 = (t & 31) * 4;
    float acc[4][4];
#pragma unroll
    for (int q = 0; q < 4; ++q)
#pragma unroll
        for (int c = 0; c < 4; ++c) acc[q][c] = 0.0f;
    for (int e = 0; e < NEIG; ++e) {
        float4 sv = *(float4*)&sShs[e * HDIM + f0];
#pragma unroll
        for (int q = 0; q < 4; ++q) {
            float evv = sEv[(nb + q) * NEIG + e];
            acc[q][0] += evv * sv.x;
            acc[q][1] += evv * sv.y;
            acc[q][2] += evv * sv.z;
            acc[q][3] += evv * sv.w;
        }
    }
#pragma unroll
    for (int q = 0; q < 4; ++q) {
        int n = n0 + nb + q;
        if (n < N_NODES) {
            ushort4 o;
            o.x = f2bf(acc[q][0]); o.y = f2bf(acc[q][1]);
            o.z = f2bf(acc[q][2]); o.w = f2bf(acc[q][3]);
            *(ushort4*)&Xb[(size_t)n * XB_COLS + 4 * IN_F + f0] = o;
        }
    }
}

// MFMA bf16 GEMM with fused BN column-stats (shfl + per-wave LDS, no LDS atomics)
__global__ __launch_bounds__(256) void k_gemm(const unsigned short* __restrict__ Xb,
                                              const unsigned short* __restrict__ Wt,
                                              const float* __restrict__ bias,
                                              float* __restrict__ out,
                                              float* __restrict__ colsum,
                                              float* __restrict__ colsq) {
    __shared__ unsigned short sA[128 * 32];
    __shared__ unsigned short sB[128 * 32];
    __shared__ float cs[4][OUT_F];
    __shared__ float cq[4][OUT_F];
    int tid = threadIdx.x;
    int wave = tid >> 6, lane = tid & 63;
    int quad = lane >> 4, m16 = lane & 15;
    int row0 = blockIdx.x * 128;

    floatx4 acc[2][8];
#pragma unroll
    for (int mt = 0; mt < 2; ++mt)
#pragma unroll
        for (int nt = 0; nt < 8; ++nt) acc[mt][nt] = (floatx4)(0.0f);

    int r  = tid >> 2;
    int c8 = (tid & 3) * 8;
    int gr0 = min(row0 + r, N_NODES - 1);
    int gr1 = min(row0 + r + 64, N_NODES - 1);

    for (int k0 = 0; k0 < 640; k0 += 32) {
        *(uint4*)&sA[r * 32 + c8]        = *(const uint4*)&Xb[(size_t)gr0 * XB_COLS + k0 + c8];
        *(uint4*)&sA[(r + 64) * 32 + c8] = *(const uint4*)&Xb[(size_t)gr1 * XB_COLS + k0 + c8];
        *(uint4*)&sB[r * 32 + c8]        = *(const uint4*)&Wt[r * 640 + k0 + c8];
        *(uint4*)&sB[(r + 64) * 32 + c8] = *(const uint4*)&Wt[(r + 64) * 640 + k0 + c8];
        __syncthreads();
        short8 a0 = *(short8*)&sA[(wave * 32 + m16) * 32 + quad * 8];
        short8 a1 = *(short8*)&sA[(wave * 32 + 16 + m16) * 32 + quad * 8];
#pragma unroll
        for (int nt = 0; nt < 8; ++nt) {
            short8 b = *(short8*)&sB[(nt * 16 + m16) * 32 + quad * 8];
            acc[0][nt] = __builtin_amdgcn_mfma_f32_16x16x32_bf16(a0, b, acc[0][nt], 0, 0, 0);
            acc[1][nt] = __builtin_amdgcn_mfma_f32_16x16x32_bf16(a1, b, acc[1][nt], 0, 0, 0);
        }
        __syncthreads();
    }
#pragma unroll
    for (int nt = 0; nt < 8; ++nt) {
        int col = nt * 16 + m16;
        float bb = bias[col];
        float sv = 0.0f, sq = 0.0f;
#pragma unroll
        for (int mt = 0; mt < 2; ++mt) {
            int rbase = row0 + wave * 32 + mt * 16 + quad * 4;
#pragma unroll
            for (int reg = 0; reg < 4; ++reg) {
                int row = rbase + reg;
                if (row < N_NODES) {
                    float w = acc[mt][nt][reg] + bb;
                    out[(size_t)row * OUT_F + col] = w;
                    sv += w;
                    sq += w * w;
                }
            }
        }
        sv += __shfl_down(sv, 32); sq += __shfl_down(sq, 32);
        sv += __shfl_down(sv, 16); sq += __shfl_down(sq, 16);
        if (lane < 16) { cs[wave][col] = sv; cq[wave][col] = sq; }
    }
    __syncthreads();
    if (tid < OUT_F) {
        float s = cs[0][tid] + cs[1][tid] + cs[2][tid] + cs[3][tid];
        float q = cq[0][tid] + cq[1][tid] + cq[2][tid] + cq[3][tid];
        atomicAdd(&colsum[tid], s);
        atomicAdd(&colsq[tid], q);
    }
}

__global__ void k_bn_apply(float* __restrict__ out, const float* __restrict__ colsum,
                           const float* __restrict__ colsq, const float* __restrict__ gamma,
                           const float* __restrict__ beta) {
    int t = blockIdx.x * 256 + threadIdx.x;
    int n = t >> 5, c = t & 31;
    float4 v = *(float4*)&out[n * OUT_F + c * 4];
    float4 s = *(const float4*)&colsum[c * 4];
    float4 q = *(const float4*)&colsq[c * 4];
    float4 g = *(const float4*)&gamma[c * 4];
    float4 b = *(const float4*)&beta[c * 4];
    const float invN = 1.0f / (float)N_NODES;
    float mux = s.x * invN, muy = s.y * invN, muz = s.z * invN, muw = s.w * invN;
    float ix = rsqrtf(q.x * invN - mux * mux + BN_EPSF);
    float iy = rsqrtf(q.y * invN - muy * muy + BN_EPSF);
    float iz = rsqrtf(q.z * invN - muz * muz + BN_EPSF);
    float iw = rsqrtf(q.w * invN - muw * muw + BN_EPSF);
    v.x = fmaxf(0.0f, (v.x - mux) * ix * g.x + b.x);
    v.y = fmaxf(0.0f, (v.y - muy) * iy * g.y + b.y);
    v.z = fmaxf(0.0f, (v.z - muz) * iz * g.z + b.z);
    v.w = fmaxf(0.0f, (v.w - muw) * iw * g.w + b.w);
    *(float4*)&out[n * OUT_F + c * 4] = v;
}

extern "C" void kernel_launch(void* const* d_in, const int* in_sizes, int n_in,
                              void* d_out, int out_size, void* d_ws, size_t ws_size,
                              hipStream_t stream) {
    const float* feature    = (const float*)d_in[0];
    const float* lin_w      = (const float*)d_in[1];
    const float* lin_b      = (const float*)d_in[2];
    const float* ew0        = (const float*)d_in[3];
    const float* eb0        = (const float*)d_in[4];
    const float* ew1        = (const float*)d_in[5];
    const float* eb1        = (const float*)d_in[6];
    const float* ew2        = (const float*)d_in[7];
    const float* eb2        = (const float*)d_in[8];
    const float* bn_gamma   = (const float*)d_in[9];
    const float* bn_beta    = (const float*)d_in[10];
    const float* lambda_max = (const float*)d_in[11];
    const float* evecs      = (const float*)d_in[12];
    const float* evals      = (const float*)d_in[13];
    const int*   edge_src   = (const int*)d_in[14];
    const int*   edge_dst   = (const int*)d_in[15];

    float* out = (float*)d_out;
    float* ws  = (float*)d_ws;
    unsigned short* Xb = (unsigned short*)(ws + OFF_XB);
    unsigned short* Wt = (unsigned short*)(ws + OFF_WT);
    float* dsq      = ws + OFF_DSQRT;
    float* hs_small = ws + OFF_HS;
    float* ef       = ws + OFF_EF;
    float* colsum   = ws + OFF_COLSUM;
    float* colsq    = ws + OFF_COLSQ;
    int*   deg      = (int*)(ws + OFF_DEG);
    int*   row_start= (int*)(ws + OFF_ROWSTART);
    int*   csr_src  = (int*)(ws + OFF_CSR);
    int*   bsum     = (int*)(ws + OFF_BSUM);
    int*   rank     = (int*)(ws + OFF_RANK);
    float* partials = ws + OFF_X1F;

    // ---- prep (feat->bf16, W->Wt bf16, zero deg/stats) + CSR build ----
    k_prep<<<3674, 256, 0, stream>>>(feature, lin_w, Xb, Wt, deg, hs_small);
    k_rank<<<(N_EDGES + 255) / 256, 256, 0, stream>>>(deg, edge_dst, rank);
    k_scan1<<<SCAN_BLK, 1024, 0, stream>>>(deg, row_start, bsum);
    k_scan2<<<1, 64, 0, stream>>>(bsum);
    k_scan3<<<SCAN_BLK, 1024, 0, stream>>>(deg, row_start, bsum, dsq);
    k_csr<<<(N_EDGES + 255) / 256, 256, 0, stream>>>(edge_src, edge_dst, rank, row_start, csr_src);

    // ---- Chebyshev recurrence (all-bf16 state in Xb column slots) ----
    const int GBLK = (N_NODES * 64 + 255) / 256;
    k_gather<<<GBLK, 256, 0, stream>>>(row_start, csr_src, dsq,
                                       Xb + 0, Xb + 0, (const unsigned short*)nullptr,
                                       Xb + IN_F, lambda_max, 1);
    k_gather<<<GBLK, 256, 0, stream>>>(row_start, csr_src, dsq,
                                       Xb + IN_F, Xb + IN_F, Xb + 0,
                                       Xb + 2 * IN_F, lambda_max, 0);
    k_gather<<<GBLK, 256, 0, stream>>>(row_start, csr_src, dsq,
                                       Xb + 2 * IN_F, Xb + 2 * IN_F, Xb + IN_F,
                                       Xb + 3 * IN_F, lambda_max, 0);

    // ---- eigen block ----
    k_ef2<<<NEIG, 128, 0, stream>>>(evals, ew0, eb0, ew1, eb1, ew2, eb2, ef);
    k_hs_partial2<<<HSP_BLOCKS, 256, 0, stream>>>(evecs, feature, partials);
    k_hs_reduce<<<32 * RED_SPLIT, 256, 0, stream>>>(partials, hs_small);
    k_hs_apply2<<<(N_NODES + 31) / 32, 256, 0, stream>>>(Xb, evecs, hs_small, ef);

    // ---- MFMA linear (+BN stats) + BN apply ----
    k_gemm<<<(N_NODES + 127) / 128, 256, 0, stream>>>(Xb, Wt, lin_b, out, colsum, colsq);
    k_bn_apply<<<(N_NODES * 32) / 256, 256, 0, stream>>>(out, colsum, colsq, bn_gamma, bn_beta);
}